// Round 4
// baseline (150.620 us; speedup 1.0000x reference)
//
#include <hip/hip_runtime.h>

typedef __bf16 bf16;
typedef __attribute__((ext_vector_type(8))) __bf16 bf16x8;
typedef __attribute__((ext_vector_type(4))) __bf16 bf16x4;
typedef __attribute__((ext_vector_type(2))) __bf16 bf16x2;
typedef __attribute__((ext_vector_type(4))) float  f32x4;

#define MFMA16(A,B,C) __builtin_amdgcn_mfma_f32_16x16x32_bf16(A,B,C,0,0,0)

// problem constants
constexpr int ROWS = 262144;
constexpr int DIN  = 38;   // real K of layer 1 (padded to 64)
constexpr int H1N  = 256;
constexpr int H2N  = 256;
constexpr int PN   = 128;
constexpr int BM   = 32;   // rows per tile
constexpr int NBLK = 1024; // persistent blocks
constexpr int NT   = ROWS / (NBLK * BM);   // 8 tiles per block

// ws layout (bytes)
constexpr int W1P_OFF = 0;        // 16nt*2ks*64lanes*16B = 32768
constexpr int W2P_OFF = 32768;    // 16*8*64*16 = 131072
constexpr int VP_OFF  = 163840;   // 8*64*16 = 8192
constexpr int C_OFF   = 172032;   // 6 floats

// ---------------------------------------------------------------------------
// Prep (blockIdx-branched, wave-uniform) — unchanged from R2 (fast)
// ---------------------------------------------------------------------------
__global__ void prep_kernel(const float* __restrict__ W1,
                            const float* __restrict__ W2,
                            const float* __restrict__ W3,
                            const float* __restrict__ b3,
                            const float* __restrict__ lw_i, const float* __restrict__ bew_i,
                            const float* __restrict__ lw_e, const float* __restrict__ bew_e,
                            const float* __restrict__ lw_m, const float* __restrict__ bew_m,
                            unsigned char* __restrict__ ws)
{
    const int b   = blockIdx.x;
    const int tid = threadIdx.x;

    if (b < 8) {                         // ---- W1 pack ----
        const int u = b * 256 + tid;
        const int lane = u & 63, ks = (u >> 6) & 1, nt = u >> 7;
        const int n  = nt * 16 + (lane & 15);
        const int kb = ks * 32 + (lane >> 4) * 8;
        bf16x8 v;
        #pragma unroll
        for (int i = 0; i < 8; ++i) {
            const int k = kb + i;
            v[i] = (bf16)(k < DIN ? W1[n * DIN + k] : 0.f);
        }
        ((bf16x8*)(ws + W1P_OFF))[u] = v;
    } else if (b < 40) {                 // ---- W2 pack ----
        const int u = (b - 8) * 256 + tid;
        const int lane = u & 63, ks = (u >> 6) & 7, nt = u >> 9;
        const int n  = nt * 16 + (lane & 15);
        const int kb = ks * 32 + (lane >> 4) * 8;
        const float4 v0 = *(const float4*)(W2 + n * H1N + kb);
        const float4 v1 = *(const float4*)(W2 + n * H1N + kb + 4);
        bf16x8 v;
        v[0] = (bf16)v0.x; v[1] = (bf16)v0.y; v[2] = (bf16)v0.z; v[3] = (bf16)v0.w;
        v[4] = (bf16)v1.x; v[5] = (bf16)v1.y; v[6] = (bf16)v1.z; v[7] = (bf16)v1.w;
        ((bf16x8*)(ws + W2P_OFF))[u] = v;
    } else if (b == 40) {                // ---- V fold ----
        __shared__ float wv[6][PN];
        const float* __restrict__ srcs[6] = {lw_i, bew_i, lw_e, bew_e, lw_m, bew_m};
        if (tid < PN) {
            #pragma unroll
            for (int h = 0; h < 6; ++h) wv[h][tid] = srcs[h][tid];
        }
        __syncthreads();
        const int k = tid;
        float s[6] = {0.f, 0.f, 0.f, 0.f, 0.f, 0.f};
        #pragma unroll 4
        for (int p = 0; p < PN; ++p) {
            const float w3 = W3[p * H2N + k];
            #pragma unroll
            for (int h = 0; h < 6; ++h) s[h] += wv[h][p] * w3;
        }
        const int ks = k >> 5, lq = (k >> 3) & 3, i = k & 7;
        unsigned char* vp = ws + VP_OFF;
        #pragma unroll
        for (int h = 0; h < 6; ++h)
            *(bf16*)(vp + (ks * 64 + lq * 16 + h) * 16 + i * 2) = (bf16)s[h];
        #pragma unroll
        for (int h = 6; h < 16; ++h)
            *(bf16*)(vp + (ks * 64 + lq * 16 + h) * 16 + i * 2) = (bf16)0.f;
    } else {                             // ---- c scalars ----
        __shared__ float red[6][PN];
        const float* __restrict__ srcs[6] = {lw_i, bew_i, lw_e, bew_e, lw_m, bew_m};
        if (tid < PN) {
            const float bv = b3[tid];
            #pragma unroll
            for (int h = 0; h < 6; ++h) red[h][tid] = bv * srcs[h][tid];
        }
        __syncthreads();
        if (tid < 6) {
            float s = 0.f;
            for (int p = 0; p < PN; ++p) s += red[tid][p];
            ((float*)(ws + C_OFF))[tid] = s;
        }
    }
}

// ---------------------------------------------------------------------------
// Persistent fused MLP: 1024 blocks x 8 tiles of 32 rows.
// Weights register-resident per wave (w1f: 32 VGPR, w2f: 128 VGPR), V in LDS.
// X double-buffered: tile t+1 loaded to regs at top of iter t, stored to the
// alternate LDS buffer after the L2 barrier.
// Per tile: 3 barriers. LDS 48 KB -> 2 blocks/CU (VGPR-limited to 2 w/SIMD).
// ---------------------------------------------------------------------------
__global__ __launch_bounds__(256, 2)
void fused_kernel(const float* __restrict__ X,
                  const float* __restrict__ b1,
                  const float* __restrict__ b2,
                  const unsigned char* __restrict__ ws,
                  const float* __restrict__ lb_i, const float* __restrict__ beb_i,
                  const float* __restrict__ bw_i, const float* __restrict__ bb_i,
                  const float* __restrict__ lb_e, const float* __restrict__ beb_e,
                  const float* __restrict__ bw_e, const float* __restrict__ bb_e,
                  const float* __restrict__ lb_m, const float* __restrict__ beb_m,
                  const float* __restrict__ bw_m, const float* __restrict__ bb_m,
                  float* __restrict__ out)
{
    __shared__ __attribute__((aligned(16))) unsigned char sX[2][4096];   //  8 KB
    __shared__ __attribute__((aligned(16))) unsigned char sH1[16384];    // 16 KB
    __shared__ __attribute__((aligned(16))) unsigned char sH2[16384];    // 16 KB
    __shared__ __attribute__((aligned(16))) unsigned char sV[8192];      //  8 KB

    const int tid  = threadIdx.x;
    const int lane = tid & 63;
    const int wid  = tid >> 6;
    const int lr   = lane & 15;
    const int lq   = lane >> 4;
    const int nb   = wid * 4;

    const bf16x8* __restrict__ W1p = (const bf16x8*)(ws + W1P_OFF);
    const bf16x8* __restrict__ W2p = (const bf16x8*)(ws + W2P_OFF);
    const bf16x8* __restrict__ Vp  = (const bf16x8*)(ws + VP_OFF);
    const float*  __restrict__ cvec = (const float*)(ws + C_OFF);

    // ---- resident weight fragments (per-wave 4-ntile slice) ----
    bf16x8 w1f[4][2];
    bf16x8 w2f[4][8];
    #pragma unroll
    for (int j = 0; j < 4; ++j)
        #pragma unroll
        for (int ks = 0; ks < 2; ++ks)
            w1f[j][ks] = W1p[((nb + j) * 2 + ks) * 64 + lane];
    #pragma unroll
    for (int j = 0; j < 4; ++j)
        #pragma unroll
        for (int ks = 0; ks < 8; ++ks)
            w2f[j][ks] = W2p[((nb + j) * 8 + ks) * 64 + lane];

    // ---- V fragments to LDS (512 x 16B) ----
    ((bf16x8*)sV)[tid]       = Vp[tid];
    ((bf16x8*)sV)[tid + 256] = Vp[tid + 256];

    // ---- hoisted head scalars (uniform) ----
    const float hlb[3]  = {lb_i[0],  lb_e[0],  lb_m[0]};
    const float hbeb[3] = {beb_i[0], beb_e[0], beb_m[0]};
    const float hbw[3]  = {bw_i[0],  bw_e[0],  bw_m[0]};
    const float hbb[3]  = {bb_i[0],  bb_e[0],  bb_m[0]};
    const float hc[6]   = {cvec[0], cvec[1], cvec[2], cvec[3], cvec[4], cvec[5]};

    // ---- stage tile 0 ----
    {
        const int rowbase = blockIdx.x * NT * BM;
        #pragma unroll
        for (int it = 0; it < 4; ++it) {
            const int idx = it * 256 + tid;
            const int r = idx >> 5, cp = idx & 31, k0 = cp * 2;
            const float* xr = X + (size_t)(rowbase + r) * DIN;
            bf16x2 pv;
            if (k0 + 1 < DIN) {
                const float2 xv = *(const float2*)(xr + k0);
                pv[0] = (bf16)xv.x; pv[1] = (bf16)xv.y;
            } else { pv[0] = (bf16)0.f; pv[1] = (bf16)0.f; }
            *(bf16x2*)(sX[0] + (((r << 7) + (cp << 2)) ^ ((r & 7) << 4))) = pv;
        }
    }
    __syncthreads();

    int cur = 0;
    for (int t = 0; t < NT; ++t) {
        const int rowbase = (blockIdx.x * NT + t) * BM;
        const bool headlane = (lq == 0) && (wid < 2);
        const int  headrow  = rowbase + wid * 16 + lr;

        // epilogue X scalars for THIS tile (used at the very end; L2-hot)
        float ep0 = 0.f, ep7 = 0.f, ep9 = 0.f, ep12 = 0.f;
        if (headlane) {
            const float* xr = X + (size_t)headrow * DIN;
            ep0 = xr[0]; ep7 = xr[7]; ep9 = xr[9]; ep12 = xr[12];
        }

        // prefetch NEXT tile's X into regs (latency hides under L1+L2 phases)
        float2 xv[4];
        const bool pf = (t + 1 < NT);
        if (pf) {
            const int rbn = rowbase + BM;
            #pragma unroll
            for (int it = 0; it < 4; ++it) {
                const int idx = it * 256 + tid;
                const int r = idx >> 5, cp = idx & 31, k0 = cp * 2;
                if (k0 + 1 < DIN)
                    xv[it] = *(const float2*)(X + (size_t)(rbn + r) * DIN + k0);
                else { xv[it].x = 0.f; xv[it].y = 0.f; }
            }
        }

        // ---- layer 1 (reads sX[cur], reg weights) ----
        {
            f32x4 acc1[4][2];
            #pragma unroll
            for (int j = 0; j < 4; ++j)
                #pragma unroll
                for (int mt = 0; mt < 2; ++mt) acc1[j][mt] = (f32x4){0.f, 0.f, 0.f, 0.f};
            unsigned char* const sXc = sX[cur];
            #pragma unroll
            for (int ks = 0; ks < 2; ++ks) {
                const int kbyte = (ks * 32 + lq * 8) * 2;
                bf16x8 xf[2];
                #pragma unroll
                for (int mt = 0; mt < 2; ++mt) {
                    const int m = mt * 16 + lr;
                    xf[mt] = *(const bf16x8*)(sXc + (((m << 7) + kbyte) ^ ((m & 7) << 4)));
                }
                #pragma unroll
                for (int j = 0; j < 4; ++j)
                    #pragma unroll
                    for (int mt = 0; mt < 2; ++mt)
                        acc1[j][mt] = MFMA16(w1f[j][ks], xf[mt], acc1[j][mt]);
            }
            #pragma unroll
            for (int j = 0; j < 4; ++j) {
                const int nbase = (nb + j) * 16 + lq * 4;
                const float4 bias = *(const float4*)(b1 + nbase);
                const float ba[4] = {bias.x, bias.y, bias.z, bias.w};
                #pragma unroll
                for (int mt = 0; mt < 2; ++mt) {
                    const int m = mt * 16 + lr;
                    bf16x4 hv;
                    #pragma unroll
                    for (int r2 = 0; r2 < 4; ++r2)
                        hv[r2] = (bf16)fmaxf(acc1[j][mt][r2] + ba[r2], 0.f);
                    *(bf16x4*)(sH1 + ((((m << 8) + nbase) << 1) ^ ((m & 7) << 4))) = hv;
                }
            }
        }
        __syncthreads();

        // ---- layer 2 (reads sH1, reg weights) ----
        {
            f32x4 acc2[4][2];
            #pragma unroll
            for (int j = 0; j < 4; ++j)
                #pragma unroll
                for (int mt = 0; mt < 2; ++mt) acc2[j][mt] = (f32x4){0.f, 0.f, 0.f, 0.f};
            #pragma unroll
            for (int ks = 0; ks < 8; ++ks) {
                const int kbyte = (ks * 32 + lq * 8) * 2;
                bf16x8 hf[2];
                #pragma unroll
                for (int mt = 0; mt < 2; ++mt) {
                    const int m = mt * 16 + lr;
                    hf[mt] = *(const bf16x8*)(sH1 + (((m << 9) + kbyte) ^ ((m & 7) << 4)));
                }
                #pragma unroll
                for (int j = 0; j < 4; ++j)
                    #pragma unroll
                    for (int mt = 0; mt < 2; ++mt)
                        acc2[j][mt] = MFMA16(w2f[j][ks], hf[mt], acc2[j][mt]);
            }
            #pragma unroll
            for (int j = 0; j < 4; ++j) {
                const int nbase = (nb + j) * 16 + lq * 4;
                const float4 bias = *(const float4*)(b2 + nbase);
                const float ba[4] = {bias.x, bias.y, bias.z, bias.w};
                #pragma unroll
                for (int mt = 0; mt < 2; ++mt) {
                    const int m = mt * 16 + lr;
                    bf16x4 hv;
                    #pragma unroll
                    for (int r2 = 0; r2 < 4; ++r2)
                        hv[r2] = (bf16)fmaxf(acc2[j][mt][r2] + ba[r2], 0.f);
                    *(bf16x4*)(sH2 + ((((m << 8) + nbase) << 1) ^ ((m & 7) << 4))) = hv;
                }
            }
        }
        __syncthreads();

        // ---- store prefetched X into the alternate buffer ----
        if (pf) {
            #pragma unroll
            for (int it = 0; it < 4; ++it) {
                const int idx = it * 256 + tid;
                const int r = idx >> 5, cp = idx & 31;
                bf16x2 pv;
                pv[0] = (bf16)xv[it].x; pv[1] = (bf16)xv[it].y;
                *(bf16x2*)(sX[cur ^ 1] + (((r << 7) + (cp << 2)) ^ ((r & 7) << 4))) = pv;
            }
        }

        // ---- folded layer3 + heads (waves 0,1) ----
        if (wid < 2) {
            f32x4 acc4 = (f32x4){0.f, 0.f, 0.f, 0.f};
            const int m = wid * 16 + lr;
            #pragma unroll
            for (int ks = 0; ks < 8; ++ks) {
                const int kbyte = (ks * 32 + lq * 8) * 2;
                const bf16x8 hf = *(const bf16x8*)(sH2 + (((m << 9) + kbyte) ^ ((m & 7) << 4)));
                const bf16x8 vf = *(const bf16x8*)(sV + (ks * 64 + lane) * 16);
                acc4 = MFMA16(vf, hf, acc4);
            }
            const float d4 = __shfl(acc4[0], lane + 16);
            const float d5 = __shfl(acc4[1], lane + 16);
            if (lq == 0) {
                const float dots[6] = {acc4[0], acc4[1], acc4[2], acc4[3], d4, d5};
                const float xres[3] = {ep7, ep9, ep12};
                #pragma unroll
                for (int h = 0; h < 3; ++h) {
                    const float lin = dots[2 * h] + hc[2 * h] + hlb[h];
                    const float e   = (dots[2 * h + 1] + hc[2 * h + 1]) * ep0 + hbeb[h];
                    const float y   = hbw[h] * e * lin + hbb[h] + xres[h];
                    out[(size_t)headrow * 3 + h] = y;
                }
            }
        }
        __syncthreads();
        cur ^= 1;
    }
}

extern "C" void kernel_launch(void* const* d_in, const int* in_sizes, int n_in,
                              void* d_out, int out_size, void* d_ws, size_t ws_size,
                              hipStream_t stream) {
    const float* X   = (const float*)d_in[0];
    const float* W1  = (const float*)d_in[1];
    const float* b1  = (const float*)d_in[2];
    const float* W2  = (const float*)d_in[3];
    const float* b2  = (const float*)d_in[4];
    const float* W3  = (const float*)d_in[5];
    const float* b3  = (const float*)d_in[6];
    const float* lw_i  = (const float*)d_in[7];
    const float* lb_i  = (const float*)d_in[8];
    const float* bew_i = (const float*)d_in[9];
    const float* beb_i = (const float*)d_in[10];
    const float* bw_i  = (const float*)d_in[11];
    const float* bb_i  = (const float*)d_in[12];
    const float* lw_e  = (const float*)d_in[13];
    const float* lb_e  = (const float*)d_in[14];
    const float* bew_e = (const float*)d_in[15];
    const float* beb_e = (const float*)d_in[16];
    const float* bw_e  = (const float*)d_in[17];
    const float* bb_e  = (const float*)d_in[18];
    const float* lw_m  = (const float*)d_in[19];
    const float* lb_m  = (const float*)d_in[20];
    const float* bew_m = (const float*)d_in[21];
    const float* beb_m = (const float*)d_in[22];
    const float* bw_m  = (const float*)d_in[23];
    const float* bb_m  = (const float*)d_in[24];

    unsigned char* ws = (unsigned char*)d_ws;
    float* outp = (float*)d_out;

    prep_kernel<<<42, 256, 0, stream>>>(W1, W2, W3, b3,
                                        lw_i, bew_i, lw_e, bew_e, lw_m, bew_m, ws);

    fused_kernel<<<NBLK, 256, 0, stream>>>(X, b1, b2, ws,
                                           lb_i, beb_i, bw_i, bb_i,
                                           lb_e, beb_e, bw_e, bb_e,
                                           lb_m, beb_m, bw_m, bb_m,
                                           outp);
}

// Round 5
// 79.599 us; speedup vs baseline: 1.8922x; 1.8922x over previous
//
#include <hip/hip_runtime.h>

typedef __bf16 bf16;
typedef __attribute__((ext_vector_type(8))) __bf16 bf16x8;
typedef __attribute__((ext_vector_type(4))) __bf16 bf16x4;
typedef __attribute__((ext_vector_type(2))) __bf16 bf16x2;
typedef __attribute__((ext_vector_type(4))) float  f32x4;

#define MFMA16(A,B,C) __builtin_amdgcn_mfma_f32_16x16x32_bf16(A,B,C,0,0,0)

// problem constants
constexpr int ROWS = 262144;
constexpr int DIN  = 38;   // real K of layer 1 (padded to 64)
constexpr int H1N  = 256;
constexpr int H2N  = 256;
constexpr int PN   = 128;
constexpr int BM   = 32;   // rows per block

// LDS row strides (bytes) — padded so bank distribution is uniform and
// addressing is purely additive (base + ks*64 immediate), no XOR.
constexpr int SXP = 144;   // X tile: 32 rows x 128B data (+16 pad)
constexpr int SHP = 528;   // H tiles: 32 rows x 512B data (+16 pad)

// ws layout (bytes)
constexpr int W1P_OFF = 0;        // 16nt*2ks*64lanes*16B = 32768
constexpr int W2P_OFF = 32768;    // 16*8*64*16 = 131072
constexpr int VP_OFF  = 163840;   // 8*64*16 = 8192
constexpr int C_OFF   = 172032;   // 6 floats

// ---------------------------------------------------------------------------
// Prep (blockIdx-branched, wave-uniform) — unchanged (fast)
// ---------------------------------------------------------------------------
__global__ void prep_kernel(const float* __restrict__ W1,
                            const float* __restrict__ W2,
                            const float* __restrict__ W3,
                            const float* __restrict__ b3,
                            const float* __restrict__ lw_i, const float* __restrict__ bew_i,
                            const float* __restrict__ lw_e, const float* __restrict__ bew_e,
                            const float* __restrict__ lw_m, const float* __restrict__ bew_m,
                            unsigned char* __restrict__ ws)
{
    const int b   = blockIdx.x;
    const int tid = threadIdx.x;

    if (b < 8) {                         // ---- W1 pack ----
        const int u = b * 256 + tid;
        const int lane = u & 63, ks = (u >> 6) & 1, nt = u >> 7;
        const int n  = nt * 16 + (lane & 15);
        const int kb = ks * 32 + (lane >> 4) * 8;
        bf16x8 v;
        #pragma unroll
        for (int i = 0; i < 8; ++i) {
            const int k = kb + i;
            v[i] = (bf16)(k < DIN ? W1[n * DIN + k] : 0.f);
        }
        ((bf16x8*)(ws + W1P_OFF))[u] = v;
    } else if (b < 40) {                 // ---- W2 pack ----
        const int u = (b - 8) * 256 + tid;
        const int lane = u & 63, ks = (u >> 6) & 7, nt = u >> 9;
        const int n  = nt * 16 + (lane & 15);
        const int kb = ks * 32 + (lane >> 4) * 8;
        const float4 v0 = *(const float4*)(W2 + n * H1N + kb);
        const float4 v1 = *(const float4*)(W2 + n * H1N + kb + 4);
        bf16x8 v;
        v[0] = (bf16)v0.x; v[1] = (bf16)v0.y; v[2] = (bf16)v0.z; v[3] = (bf16)v0.w;
        v[4] = (bf16)v1.x; v[5] = (bf16)v1.y; v[6] = (bf16)v1.z; v[7] = (bf16)v1.w;
        ((bf16x8*)(ws + W2P_OFF))[u] = v;
    } else if (b == 40) {                // ---- V fold ----
        __shared__ float wv[6][PN];
        const float* __restrict__ srcs[6] = {lw_i, bew_i, lw_e, bew_e, lw_m, bew_m};
        if (tid < PN) {
            #pragma unroll
            for (int h = 0; h < 6; ++h) wv[h][tid] = srcs[h][tid];
        }
        __syncthreads();
        const int k = tid;
        float s[6] = {0.f, 0.f, 0.f, 0.f, 0.f, 0.f};
        #pragma unroll 4
        for (int p = 0; p < PN; ++p) {
            const float w3 = W3[p * H2N + k];
            #pragma unroll
            for (int h = 0; h < 6; ++h) s[h] += wv[h][p] * w3;
        }
        const int ks = k >> 5, lq = (k >> 3) & 3, i = k & 7;
        unsigned char* vp = ws + VP_OFF;
        #pragma unroll
        for (int h = 0; h < 6; ++h)
            *(bf16*)(vp + (ks * 64 + lq * 16 + h) * 16 + i * 2) = (bf16)s[h];
        #pragma unroll
        for (int h = 6; h < 16; ++h)
            *(bf16*)(vp + (ks * 64 + lq * 16 + h) * 16 + i * 2) = (bf16)0.f;
    } else {                             // ---- c scalars ----
        __shared__ float red[6][PN];
        const float* __restrict__ srcs[6] = {lw_i, bew_i, lw_e, bew_e, lw_m, bew_m};
        if (tid < PN) {
            const float bv = b3[tid];
            #pragma unroll
            for (int h = 0; h < 6; ++h) red[h][tid] = bv * srcs[h][tid];
        }
        __syncthreads();
        if (tid < 6) {
            float s = 0.f;
            for (int p = 0; p < PN; ++p) s += red[tid][p];
            ((float*)(ws + C_OFF))[tid] = s;
        }
    }
}

// ---------------------------------------------------------------------------
// Fused MLP: 32 rows/block, 4 waves, wave tile 4nt x 2mt. 3 barriers.
// LDS: sX (padded 144B rows) + sH1/sH2 (padded 528B rows) = 38.4 KB
// -> 4 blocks/CU; VGPR<=128 -> 16 waves/CU.
// All LDS addressing additive: base(m,lq) + ks*64 immediate. Weights stream
// from L2 with a 2-stage register pipeline inside the K loop.
// ---------------------------------------------------------------------------
__global__ __launch_bounds__(256, 4)
void fused_kernel(const float* __restrict__ X,
                  const float* __restrict__ b1,
                  const float* __restrict__ b2,
                  const unsigned char* __restrict__ ws,
                  const float* __restrict__ lb_i, const float* __restrict__ beb_i,
                  const float* __restrict__ bw_i, const float* __restrict__ bb_i,
                  const float* __restrict__ lb_e, const float* __restrict__ beb_e,
                  const float* __restrict__ bw_e, const float* __restrict__ bb_e,
                  const float* __restrict__ lb_m, const float* __restrict__ beb_m,
                  const float* __restrict__ bw_m, const float* __restrict__ bb_m,
                  float* __restrict__ out)
{
    __shared__ __attribute__((aligned(16))) unsigned char sX [BM * SXP];  //  4.6 KB
    __shared__ __attribute__((aligned(16))) unsigned char sH1[BM * SHP];  // 16.9 KB
    __shared__ __attribute__((aligned(16))) unsigned char sH2[BM * SHP];  // 16.9 KB

    const int tid  = threadIdx.x;
    const int lane = tid & 63;
    const int wid  = tid >> 6;
    const int lr   = lane & 15;
    const int lq   = lane >> 4;
    const int nb   = wid * 4;
    const int rowbase = blockIdx.x * BM;

    const bf16x8* __restrict__ W1p = (const bf16x8*)(ws + W1P_OFF);
    const bf16x8* __restrict__ W2p = (const bf16x8*)(ws + W2P_OFF);
    const bf16x8* __restrict__ Vp  = (const bf16x8*)(ws + VP_OFF);
    const float*  __restrict__ cvec = (const float*)(ws + C_OFF);

    // ---- epilogue X scalars (issued first, consumed last) ----
    const bool headlane = (lq == 0) && (wid < 2);
    const int  headrow  = rowbase + wid * 16 + lr;
    float ep0 = 0.f, ep7 = 0.f, ep9 = 0.f, ep12 = 0.f;
    if (headlane) {
        const float* xr = X + (size_t)headrow * DIN;
        ep0 = xr[0]; ep7 = xr[7]; ep9 = xr[9]; ep12 = xr[12];
    }

    // ---- stage X tile: 32 rows x 64 cols (zero-padded), bf16 ----
    #pragma unroll
    for (int it = 0; it < 4; ++it) {
        const int idx = it * 256 + tid;
        const int r = idx >> 5, cp = idx & 31, k0 = cp * 2;
        bf16x2 pv;
        if (k0 + 1 < DIN) {
            const float2 xv = *(const float2*)(X + (size_t)(rowbase + r) * DIN + k0);
            pv[0] = (bf16)xv.x; pv[1] = (bf16)xv.y;
        } else { pv[0] = (bf16)0.f; pv[1] = (bf16)0.f; }
        *(bf16x2*)(sX + r * SXP + cp * 4) = pv;
    }
    __syncthreads();

    // per-mt LDS base addresses (additive; hoisted once)
    const int mA = lr, mB = 16 + lr;                  // the wave's two row groups
    const unsigned char* xbA = sX + mA * SXP + lq * 16;
    const unsigned char* xbB = sX + mB * SXP + lq * 16;
    const unsigned char* h1A = sH1 + mA * SHP + lq * 16;
    const unsigned char* h1B = sH1 + mB * SHP + lq * 16;

    // ---- layer 1: h1 = relu(X @ W1^T + b1) ----
    {
        bf16x8 w1f[4][2];
        #pragma unroll
        for (int j = 0; j < 4; ++j)
            #pragma unroll
            for (int ks = 0; ks < 2; ++ks)
                w1f[j][ks] = W1p[((nb + j) * 2 + ks) * 64 + lane];
        const int nbase = nb * 16 + lq * 4;           // wave's bias slice start
        const float4 bia0 = *(const float4*)(b1 + nbase);
        const float4 bia1 = *(const float4*)(b1 + nbase + 16);
        const float4 bia2 = *(const float4*)(b1 + nbase + 32);
        const float4 bia3 = *(const float4*)(b1 + nbase + 48);

        f32x4 acc[4][2];
        #pragma unroll
        for (int j = 0; j < 4; ++j)
            #pragma unroll
            for (int mt = 0; mt < 2; ++mt) acc[j][mt] = (f32x4){0.f, 0.f, 0.f, 0.f};
        #pragma unroll
        for (int ks = 0; ks < 2; ++ks) {
            const bf16x8 xfA = *(const bf16x8*)(xbA + ks * 64);
            const bf16x8 xfB = *(const bf16x8*)(xbB + ks * 64);
            #pragma unroll
            for (int j = 0; j < 4; ++j) {
                acc[j][0] = MFMA16(w1f[j][ks], xfA, acc[j][0]);
                acc[j][1] = MFMA16(w1f[j][ks], xfB, acc[j][1]);
            }
        }
        const float4 biasv[4] = {bia0, bia1, bia2, bia3};
        #pragma unroll
        for (int j = 0; j < 4; ++j) {
            const float ba[4] = {biasv[j].x, biasv[j].y, biasv[j].z, biasv[j].w};
            const int coff = (nbase + j * 16) * 2;
            #pragma unroll
            for (int mt = 0; mt < 2; ++mt) {
                bf16x4 hv;
                #pragma unroll
                for (int r2 = 0; r2 < 4; ++r2)
                    hv[r2] = (bf16)fmaxf(acc[j][mt][r2] + ba[r2], 0.f);
                *(bf16x4*)(sH1 + (mt * 16 + lr) * SHP + coff) = hv;
            }
        }
    }
    __syncthreads();

    // ---- layer 2: h2 = relu(h1 @ W2^T + b2), 2-stage weight pipeline ----
    {
        const int nbase = nb * 16 + lq * 4;
        const float4 bia0 = *(const float4*)(b2 + nbase);
        const float4 bia1 = *(const float4*)(b2 + nbase + 16);
        const float4 bia2 = *(const float4*)(b2 + nbase + 32);
        const float4 bia3 = *(const float4*)(b2 + nbase + 48);

        f32x4 acc[4][2];
        #pragma unroll
        for (int j = 0; j < 4; ++j)
            #pragma unroll
            for (int mt = 0; mt < 2; ++mt) acc[j][mt] = (f32x4){0.f, 0.f, 0.f, 0.f};

        bf16x8 wA[4], wB[4];
        #pragma unroll
        for (int j = 0; j < 4; ++j)
            wA[j] = W2p[((nb + j) * 8 + 0) * 64 + lane];

        #pragma unroll
        for (int kp = 0; kp < 4; ++kp) {
            const int ks = kp * 2;
            #pragma unroll
            for (int j = 0; j < 4; ++j)
                wB[j] = W2p[((nb + j) * 8 + ks + 1) * 64 + lane];
            {
                const bf16x8 hfA = *(const bf16x8*)(h1A + ks * 64);
                const bf16x8 hfB = *(const bf16x8*)(h1B + ks * 64);
                #pragma unroll
                for (int j = 0; j < 4; ++j) {
                    acc[j][0] = MFMA16(wA[j], hfA, acc[j][0]);
                    acc[j][1] = MFMA16(wA[j], hfB, acc[j][1]);
                }
            }
            if (kp < 3) {
                #pragma unroll
                for (int j = 0; j < 4; ++j)
                    wA[j] = W2p[((nb + j) * 8 + ks + 2) * 64 + lane];
            }
            {
                const bf16x8 hfA = *(const bf16x8*)(h1A + ks * 64 + 64);
                const bf16x8 hfB = *(const bf16x8*)(h1B + ks * 64 + 64);
                #pragma unroll
                for (int j = 0; j < 4; ++j) {
                    acc[j][0] = MFMA16(wB[j], hfA, acc[j][0]);
                    acc[j][1] = MFMA16(wB[j], hfB, acc[j][1]);
                }
            }
        }
        const float4 biasv[4] = {bia0, bia1, bia2, bia3};
        #pragma unroll
        for (int j = 0; j < 4; ++j) {
            const float ba[4] = {biasv[j].x, biasv[j].y, biasv[j].z, biasv[j].w};
            const int coff = (nbase + j * 16) * 2;
            #pragma unroll
            for (int mt = 0; mt < 2; ++mt) {
                bf16x4 hv;
                #pragma unroll
                for (int r2 = 0; r2 < 4; ++r2)
                    hv[r2] = (bf16)fmaxf(acc[j][mt][r2] + ba[r2], 0.f);
                *(bf16x4*)(sH2 + (mt * 16 + lr) * SHP + coff) = hv;
            }
        }
    }
    __syncthreads();

    // ---- folded layer3 + heads (waves 0,1; waves 2,3 exit) ----
    if (wid < 2) {
        f32x4 acc4 = (f32x4){0.f, 0.f, 0.f, 0.f};
        const unsigned char* h2b = sH2 + (wid * 16 + lr) * SHP + lq * 16;
        #pragma unroll
        for (int ks = 0; ks < 8; ++ks) {
            const bf16x8 hf = *(const bf16x8*)(h2b + ks * 64);
            const bf16x8 vf = Vp[ks * 64 + lane];
            acc4 = MFMA16(vf, hf, acc4);
        }
        const float d4 = __shfl(acc4[0], lane + 16);
        const float d5 = __shfl(acc4[1], lane + 16);
        if (lq == 0) {
            const float dots[6] = {acc4[0], acc4[1], acc4[2], acc4[3], d4, d5};
            const float hlb[3]  = {lb_i[0],  lb_e[0],  lb_m[0]};
            const float hbeb[3] = {beb_i[0], beb_e[0], beb_m[0]};
            const float hbw[3]  = {bw_i[0],  bw_e[0],  bw_m[0]};
            const float hbb[3]  = {bb_i[0],  bb_e[0],  bb_m[0]};
            const float xres[3] = {ep7, ep9, ep12};
            #pragma unroll
            for (int h = 0; h < 3; ++h) {
                const float lin = dots[2 * h] + cvec[2 * h] + hlb[h];
                const float e   = (dots[2 * h + 1] + cvec[2 * h + 1]) * ep0 + hbeb[h];
                const float y   = hbw[h] * e * lin + hbb[h] + xres[h];
                out[(size_t)headrow * 3 + h] = y;
            }
        }
    }
}

extern "C" void kernel_launch(void* const* d_in, const int* in_sizes, int n_in,
                              void* d_out, int out_size, void* d_ws, size_t ws_size,
                              hipStream_t stream) {
    const float* X   = (const float*)d_in[0];
    const float* W1  = (const float*)d_in[1];
    const float* b1  = (const float*)d_in[2];
    const float* W2  = (const float*)d_in[3];
    const float* b2  = (const float*)d_in[4];
    const float* W3  = (const float*)d_in[5];
    const float* b3  = (const float*)d_in[6];
    const float* lw_i  = (const float*)d_in[7];
    const float* lb_i  = (const float*)d_in[8];
    const float* bew_i = (const float*)d_in[9];
    const float* beb_i = (const float*)d_in[10];
    const float* bw_i  = (const float*)d_in[11];
    const float* bb_i  = (const float*)d_in[12];
    const float* lw_e  = (const float*)d_in[13];
    const float* lb_e  = (const float*)d_in[14];
    const float* bew_e = (const float*)d_in[15];
    const float* beb_e = (const float*)d_in[16];
    const float* bw_e  = (const float*)d_in[17];
    const float* bb_e  = (const float*)d_in[18];
    const float* lw_m  = (const float*)d_in[19];
    const float* lb_m  = (const float*)d_in[20];
    const float* bew_m = (const float*)d_in[21];
    const float* beb_m = (const float*)d_in[22];
    const float* bw_m  = (const float*)d_in[23];
    const float* bb_m  = (const float*)d_in[24];

    unsigned char* ws = (unsigned char*)d_ws;
    float* outp = (float*)d_out;

    prep_kernel<<<42, 256, 0, stream>>>(W1, W2, W3, b3,
                                        lw_i, bew_i, lw_e, bew_e, lw_m, bew_m, ws);

    fused_kernel<<<ROWS / BM, 256, 0, stream>>>(X, b1, b2, ws,
                                                lb_i, beb_i, bw_i, bb_i,
                                                lb_e, beb_e, bw_e, bb_e,
                                                lb_m, beb_m, bw_m, bb_m,
                                                outp);
}

// Round 6
// 76.970 us; speedup vs baseline: 1.9569x; 1.0342x over previous
//
#include <hip/hip_runtime.h>

typedef __bf16 bf16;
typedef __attribute__((ext_vector_type(8))) __bf16 bf16x8;
typedef __attribute__((ext_vector_type(4))) __bf16 bf16x4;
typedef __attribute__((ext_vector_type(2))) __bf16 bf16x2;
typedef __attribute__((ext_vector_type(4))) float  f32x4;

#define MFMA16(A,B,C) __builtin_amdgcn_mfma_f32_16x16x32_bf16(A,B,C,0,0,0)

// problem constants
constexpr int ROWS = 262144;
constexpr int DIN  = 38;   // real K of layer 1 (padded to 64)
constexpr int H1N  = 256;
constexpr int H2N  = 256;
constexpr int PN   = 128;
constexpr int WROWS = 32;  // rows per wave (2 mtiles)
constexpr int SHP  = 528;  // LDS row stride (512B data + 16B pad, bank-uniform)

// ws layout (bytes)
constexpr int W1P_OFF = 0;        // 16nt*2ks*64lanes*16B = 32768
constexpr int W2P_OFF = 32768;    // 16*8*64*16 = 131072
constexpr int VP_OFF  = 163840;   // 8*64*16 = 8192
constexpr int C_OFF   = 172032;   // 6 floats

// ---------------------------------------------------------------------------
// Prep (blockIdx-branched, wave-uniform) — unchanged (fast)
// ---------------------------------------------------------------------------
__global__ void prep_kernel(const float* __restrict__ W1,
                            const float* __restrict__ W2,
                            const float* __restrict__ W3,
                            const float* __restrict__ b3,
                            const float* __restrict__ lw_i, const float* __restrict__ bew_i,
                            const float* __restrict__ lw_e, const float* __restrict__ bew_e,
                            const float* __restrict__ lw_m, const float* __restrict__ bew_m,
                            unsigned char* __restrict__ ws)
{
    const int b   = blockIdx.x;
    const int tid = threadIdx.x;

    if (b < 8) {                         // ---- W1 pack ----
        const int u = b * 256 + tid;
        const int lane = u & 63, ks = (u >> 6) & 1, nt = u >> 7;
        const int n  = nt * 16 + (lane & 15);
        const int kb = ks * 32 + (lane >> 4) * 8;
        bf16x8 v;
        #pragma unroll
        for (int i = 0; i < 8; ++i) {
            const int k = kb + i;
            v[i] = (bf16)(k < DIN ? W1[n * DIN + k] : 0.f);
        }
        ((bf16x8*)(ws + W1P_OFF))[u] = v;
    } else if (b < 40) {                 // ---- W2 pack ----
        const int u = (b - 8) * 256 + tid;
        const int lane = u & 63, ks = (u >> 6) & 7, nt = u >> 9;
        const int n  = nt * 16 + (lane & 15);
        const int kb = ks * 32 + (lane >> 4) * 8;
        const float4 v0 = *(const float4*)(W2 + n * H1N + kb);
        const float4 v1 = *(const float4*)(W2 + n * H1N + kb + 4);
        bf16x8 v;
        v[0] = (bf16)v0.x; v[1] = (bf16)v0.y; v[2] = (bf16)v0.z; v[3] = (bf16)v0.w;
        v[4] = (bf16)v1.x; v[5] = (bf16)v1.y; v[6] = (bf16)v1.z; v[7] = (bf16)v1.w;
        ((bf16x8*)(ws + W2P_OFF))[u] = v;
    } else if (b == 40) {                // ---- V fold ----
        __shared__ float wv[6][PN];
        const float* __restrict__ srcs[6] = {lw_i, bew_i, lw_e, bew_e, lw_m, bew_m};
        if (tid < PN) {
            #pragma unroll
            for (int h = 0; h < 6; ++h) wv[h][tid] = srcs[h][tid];
        }
        __syncthreads();
        const int k = tid;
        float s[6] = {0.f, 0.f, 0.f, 0.f, 0.f, 0.f};
        #pragma unroll 4
        for (int p = 0; p < PN; ++p) {
            const float w3 = W3[p * H2N + k];
            #pragma unroll
            for (int h = 0; h < 6; ++h) s[h] += wv[h][p] * w3;
        }
        const int ks = k >> 5, lq = (k >> 3) & 3, i = k & 7;
        unsigned char* vp = ws + VP_OFF;
        #pragma unroll
        for (int h = 0; h < 6; ++h)
            *(bf16*)(vp + (ks * 64 + lq * 16 + h) * 16 + i * 2) = (bf16)s[h];
        #pragma unroll
        for (int h = 6; h < 16; ++h)
            *(bf16*)(vp + (ks * 64 + lq * 16 + h) * 16 + i * 2) = (bf16)0.f;
    } else {                             // ---- c scalars ----
        __shared__ float red[6][PN];
        const float* __restrict__ srcs[6] = {lw_i, bew_i, lw_e, bew_e, lw_m, bew_m};
        if (tid < PN) {
            const float bv = b3[tid];
            #pragma unroll
            for (int h = 0; h < 6; ++h) red[h][tid] = bv * srcs[h][tid];
        }
        __syncthreads();
        if (tid < 6) {
            float s = 0.f;
            for (int p = 0; p < PN; ++p) s += red[tid][p];
            ((float*)(ws + C_OFF))[tid] = s;
        }
    }
}

// ---------------------------------------------------------------------------
// Wave-local fused MLP: each wave owns 32 rows and computes ALL 16 ntiles of
// both layers + the folded head. ZERO __syncthreads. Per-wave LDS slab holds
// h1 (then h2 overwrites it; same-wave DS ops are ordered). X fragments come
// straight from global (K=38 -> ks0 full, ks1 only lq==0 lanes nonzero).
// LDS 4 x 16.9 KB = 67.6 KB -> 2 blocks/CU, 8 fully-independent waves/CU.
// ---------------------------------------------------------------------------
__global__ __launch_bounds__(256, 2)
void fused_kernel(const float* __restrict__ X,
                  const float* __restrict__ b1,
                  const float* __restrict__ b2,
                  const unsigned char* __restrict__ ws,
                  const float* __restrict__ lb_i, const float* __restrict__ beb_i,
                  const float* __restrict__ bw_i, const float* __restrict__ bb_i,
                  const float* __restrict__ lb_e, const float* __restrict__ beb_e,
                  const float* __restrict__ bw_e, const float* __restrict__ bb_e,
                  const float* __restrict__ lb_m, const float* __restrict__ beb_m,
                  const float* __restrict__ bw_m, const float* __restrict__ bb_m,
                  float* __restrict__ out)
{
    __shared__ __attribute__((aligned(16))) unsigned char sH[4][WROWS * SHP]; // 67.6 KB

    const int tid  = threadIdx.x;
    const int lane = tid & 63;
    const int wid  = tid >> 6;
    const int lr   = lane & 15;
    const int lq   = lane >> 4;
    unsigned char* const myH = sH[wid];
    const int rowbase = (blockIdx.x * 4 + wid) * WROWS;

    const bf16x8* __restrict__ W1p = (const bf16x8*)(ws + W1P_OFF);
    const bf16x8* __restrict__ W2p = (const bf16x8*)(ws + W2P_OFF);
    const bf16x8* __restrict__ Vp  = (const bf16x8*)(ws + VP_OFF);
    const float*  __restrict__ cvec = (const float*)(ws + C_OFF);

    // ---- epilogue X scalars for both mtiles (lq==0 lanes), issued early ----
    float ep0[2] = {0.f, 0.f}, ep7[2] = {0.f, 0.f};
    float ep9[2] = {0.f, 0.f}, ep12[2] = {0.f, 0.f};
    if (lq == 0) {
        #pragma unroll
        for (int mt = 0; mt < 2; ++mt) {
            const float* xr = X + (size_t)(rowbase + mt * 16 + lr) * DIN;
            ep0[mt] = xr[0]; ep7[mt] = xr[7]; ep9[mt] = xr[9]; ep12[mt] = xr[12];
        }
    }

    // ---- X fragments direct from global (no LDS, no barrier) ----
    bf16x8 xf[2][2];   // [mt][ks]
    #pragma unroll
    for (int mt = 0; mt < 2; ++mt) {
        const float* xr = X + (size_t)(rowbase + mt * 16 + lr) * DIN;
        const float2 a0 = *(const float2*)(xr + lq * 8 + 0);
        const float2 a1 = *(const float2*)(xr + lq * 8 + 2);
        const float2 a2 = *(const float2*)(xr + lq * 8 + 4);
        const float2 a3 = *(const float2*)(xr + lq * 8 + 6);
        bf16x8 v0;
        v0[0] = (bf16)a0.x; v0[1] = (bf16)a0.y; v0[2] = (bf16)a1.x; v0[3] = (bf16)a1.y;
        v0[4] = (bf16)a2.x; v0[5] = (bf16)a2.y; v0[6] = (bf16)a3.x; v0[7] = (bf16)a3.y;
        xf[mt][0] = v0;
        bf16x8 v1;
        #pragma unroll
        for (int i = 0; i < 8; ++i) v1[i] = (bf16)0.f;
        if (lq == 0) {
            const float2 c0 = *(const float2*)(xr + 32);
            const float2 c1 = *(const float2*)(xr + 34);
            const float2 c2 = *(const float2*)(xr + 36);
            v1[0] = (bf16)c0.x; v1[1] = (bf16)c0.y; v1[2] = (bf16)c1.x;
            v1[3] = (bf16)c1.y; v1[4] = (bf16)c2.x; v1[5] = (bf16)c2.y;
        }
        xf[mt][1] = v1;
    }

    // ---- layer 1: all 16 ntiles, h1 -> wave-private LDS slab ----
    #pragma unroll
    for (int j = 0; j < 16; ++j) {
        const bf16x8 w0 = W1p[(j * 2 + 0) * 64 + lane];
        const bf16x8 w1 = W1p[(j * 2 + 1) * 64 + lane];
        f32x4 a0 = (f32x4){0.f, 0.f, 0.f, 0.f};
        f32x4 a1 = (f32x4){0.f, 0.f, 0.f, 0.f};
        a0 = MFMA16(w0, xf[0][0], a0); a0 = MFMA16(w1, xf[0][1], a0);
        a1 = MFMA16(w0, xf[1][0], a1); a1 = MFMA16(w1, xf[1][1], a1);
        const float4 bias = *(const float4*)(b1 + j * 16 + lq * 4);
        const float ba[4] = {bias.x, bias.y, bias.z, bias.w};
        const int coff = (j * 16 + lq * 4) * 2;
        bf16x4 h0, h1v;
        #pragma unroll
        for (int r2 = 0; r2 < 4; ++r2) {
            h0[r2]  = (bf16)fmaxf(a0[r2] + ba[r2], 0.f);
            h1v[r2] = (bf16)fmaxf(a1[r2] + ba[r2], 0.f);
        }
        *(bf16x4*)(myH + lr * SHP + coff)        = h0;
        *(bf16x4*)(myH + (16 + lr) * SHP + coff) = h1v;
    }

    // ---- h1 fragments -> registers (64 VGPR), then slab is reusable ----
    bf16x8 hf[2][8];   // [mt][ks]
    #pragma unroll
    for (int ks = 0; ks < 8; ++ks) {
        hf[0][ks] = *(const bf16x8*)(myH + lr * SHP        + ks * 64 + lq * 16);
        hf[1][ks] = *(const bf16x8*)(myH + (16 + lr) * SHP + ks * 64 + lq * 16);
    }

    // ---- layer 2: all 16 ntiles, h2 overwrites the slab ----
    #pragma unroll
    for (int j = 0; j < 16; ++j) {
        f32x4 a0 = (f32x4){0.f, 0.f, 0.f, 0.f};
        f32x4 a1 = (f32x4){0.f, 0.f, 0.f, 0.f};
        #pragma unroll
        for (int ks = 0; ks < 8; ++ks) {
            const bf16x8 w = W2p[(j * 8 + ks) * 64 + lane];
            a0 = MFMA16(w, hf[0][ks], a0);
            a1 = MFMA16(w, hf[1][ks], a1);
        }
        const float4 bias = *(const float4*)(b2 + j * 16 + lq * 4);
        const float ba[4] = {bias.x, bias.y, bias.z, bias.w};
        const int coff = (j * 16 + lq * 4) * 2;
        bf16x4 h0, h1v;
        #pragma unroll
        for (int r2 = 0; r2 < 4; ++r2) {
            h0[r2]  = (bf16)fmaxf(a0[r2] + ba[r2], 0.f);
            h1v[r2] = (bf16)fmaxf(a1[r2] + ba[r2], 0.f);
        }
        *(bf16x4*)(myH + lr * SHP + coff)        = h0;
        *(bf16x4*)(myH + (16 + lr) * SHP + coff) = h1v;
    }

    // ---- folded layer3 + heads ----
    {
        f32x4 acc[2] = {(f32x4){0.f, 0.f, 0.f, 0.f}, (f32x4){0.f, 0.f, 0.f, 0.f}};
        #pragma unroll
        for (int ks = 0; ks < 8; ++ks) {
            const bf16x8 vf = Vp[ks * 64 + lane];
            const bf16x8 h0 = *(const bf16x8*)(myH + lr * SHP        + ks * 64 + lq * 16);
            const bf16x8 h1v = *(const bf16x8*)(myH + (16 + lr) * SHP + ks * 64 + lq * 16);
            acc[0] = MFMA16(vf, h0,  acc[0]);
            acc[1] = MFMA16(vf, h1v, acc[1]);
        }
        const float hlb[3]  = {lb_i[0],  lb_e[0],  lb_m[0]};
        const float hbeb[3] = {beb_i[0], beb_e[0], beb_m[0]};
        const float hbw[3]  = {bw_i[0],  bw_e[0],  bw_m[0]};
        const float hbb[3]  = {bb_i[0],  bb_e[0],  bb_m[0]};
        #pragma unroll
        for (int mt = 0; mt < 2; ++mt) {
            const float d4 = __shfl(acc[mt][0], lane + 16);
            const float d5 = __shfl(acc[mt][1], lane + 16);
            if (lq == 0) {
                const float dots[6] = {acc[mt][0], acc[mt][1], acc[mt][2], acc[mt][3], d4, d5};
                const float xres[3] = {ep7[mt], ep9[mt], ep12[mt]};
                const int row = rowbase + mt * 16 + lr;
                #pragma unroll
                for (int h = 0; h < 3; ++h) {
                    const float lin = dots[2 * h] + cvec[2 * h] + hlb[h];
                    const float e   = (dots[2 * h + 1] + cvec[2 * h + 1]) * ep0[mt] + hbeb[h];
                    const float y   = hbw[h] * e * lin + hbb[h] + xres[h];
                    out[(size_t)row * 3 + h] = y;
                }
            }
        }
    }
}

extern "C" void kernel_launch(void* const* d_in, const int* in_sizes, int n_in,
                              void* d_out, int out_size, void* d_ws, size_t ws_size,
                              hipStream_t stream) {
    const float* X   = (const float*)d_in[0];
    const float* W1  = (const float*)d_in[1];
    const float* b1  = (const float*)d_in[2];
    const float* W2  = (const float*)d_in[3];
    const float* b2  = (const float*)d_in[4];
    const float* W3  = (const float*)d_in[5];
    const float* b3  = (const float*)d_in[6];
    const float* lw_i  = (const float*)d_in[7];
    const float* lb_i  = (const float*)d_in[8];
    const float* bew_i = (const float*)d_in[9];
    const float* beb_i = (const float*)d_in[10];
    const float* bw_i  = (const float*)d_in[11];
    const float* bb_i  = (const float*)d_in[12];
    const float* lw_e  = (const float*)d_in[13];
    const float* lb_e  = (const float*)d_in[14];
    const float* bew_e = (const float*)d_in[15];
    const float* beb_e = (const float*)d_in[16];
    const float* bw_e  = (const float*)d_in[17];
    const float* bb_e  = (const float*)d_in[18];
    const float* lw_m  = (const float*)d_in[19];
    const float* lb_m  = (const float*)d_in[20];
    const float* bew_m = (const float*)d_in[21];
    const float* beb_m = (const float*)d_in[22];
    const float* bw_m  = (const float*)d_in[23];
    const float* bb_m  = (const float*)d_in[24];

    unsigned char* ws = (unsigned char*)d_ws;
    float* outp = (float*)d_out;

    prep_kernel<<<42, 256, 0, stream>>>(W1, W2, W3, b3,
                                        lw_i, bew_i, lw_e, bew_e, lw_m, bew_m, ws);

    // 8192 waves, 4 per block, each wave fully independent (no barriers)
    fused_kernel<<<ROWS / (4 * WROWS), 256, 0, stream>>>(X, b1, b2, ws,
                                                         lb_i, beb_i, bw_i, bb_i,
                                                         lb_e, beb_e, bw_e, bb_e,
                                                         lb_m, beb_m, bw_m, bb_m,
                                                         outp);
}